// Round 14
// baseline (117.354 us; speedup 1.0000x reference)
//
#include <hip/hip_runtime.h>

#define BB 4
#define MM 1024
#define NN 65536
#define CL (BB * MM)   // 4096 clusters
#define NPC 13         // 6 quadric + 3 n*d + 3 n + count
#define PBLK 16        // partial blocks per batch

// ---------------------------------------------------------------------------
// Kernel 1: argmin over M. K=8 samples/thread (one broadcast ds_read_b128
// feeds 8 score FMAs), split-M x8 (wave g scans m in [g*128,(g+1)*128)).
// 512 blocks x 512 threads. Writes idx only (no atomics).
// ---------------------------------------------------------------------------
__global__ __launch_bounds__(512) void k_assign(
    const float* __restrict__ pp, const float* __restrict__ smp,
    int* __restrict__ idx)
{
    __shared__ float4 pts[MM];
    __shared__ float bestSh[8][512];
    __shared__ int   biSh[8][512];

    const int b   = blockIdx.x >> 7;    // 128 blocks per batch
    const int blk = blockIdx.x & 127;   // each block: 512 samples
    const float* P = pp + b * MM * 3;
    for (int i = threadIdx.x; i < MM; i += 512) {
        float x = P[i * 3 + 0], y = P[i * 3 + 1], z = P[i * 3 + 2];
        pts[i] = make_float4(x, y, z, x * x + y * y + z * z);
    }
    __syncthreads();

    const int l  = threadIdx.x & 63;
    const int g  = threadIdx.x >> 6;           // wave id = M-octant
    const int nb = blk * 512;
    const float* S = smp + (size_t)b * NN * 3;

    float ax[8], ay[8], az[8], best[8];
    int bi[8];
#pragma unroll
    for (int j = 0; j < 8; ++j) {
        int n = nb + j * 64 + l;
        ax[j] = -2.0f * S[n * 3 + 0];
        ay[j] = -2.0f * S[n * 3 + 1];
        az[j] = -2.0f * S[n * 3 + 2];
        best[j] = 3.4e38f;
        bi[j] = 0;
    }
    const int m0 = g * 128;
#pragma unroll 2
    for (int mi = 0; mi < 128; ++mi) {
        float4 p = pts[m0 + mi];
#pragma unroll
        for (int j = 0; j < 8; ++j) {
            float sc = fmaf(ax[j], p.x, fmaf(ay[j], p.y, fmaf(az[j], p.z, p.w)));
            if (sc < best[j]) { best[j] = sc; bi[j] = m0 + mi; }
        }
    }
#pragma unroll
    for (int j = 0; j < 8; ++j) {
        bestSh[g][j * 64 + l] = best[j];
        biSh[g][j * 64 + l]   = bi[j];
    }
    __syncthreads();

    {
        const int t = threadIdx.x;             // sample-local id in [0,512)
        float bb = bestSh[0][t];
        int   ii = biSh[0][t];
#pragma unroll
        for (int gg = 1; gg < 8; ++gg) {
            float bo = bestSh[gg][t];
            int   io = biSh[gg][t];
            if (bo < bb) { bb = bo; ii = io; } // tie -> lower g = lower m
        }
        idx[b * NN + nb + t] = ii;
    }
}

// ---------------------------------------------------------------------------
// Kernel 2: per-block LDS accumulation of the 13 per-cluster sums.
// 64 blocks x 256 threads; each block covers 4096 samples of one batch,
// accumulates into a [1024][13] fp32 LDS table (stride 13 coprime with 32
// banks -> conflict-free ds_add_f32), then flushes to its partial slot.
// Partials fully overwritten -> no memset needed anywhere.
// ---------------------------------------------------------------------------
__global__ __launch_bounds__(256) void k_accum(
    const int* __restrict__ idx, const float* __restrict__ smp,
    const float* __restrict__ nrm, float* __restrict__ partial)
{
    __shared__ float tab[MM * NPC];     // 53248 B
    const int b  = blockIdx.x >> 4;     // batch
    const int pb = blockIdx.x & 15;     // partial-block within batch
    for (int i = threadIdx.x; i < MM * NPC; i += 256) tab[i] = 0.0f;
    __syncthreads();

    const float* S  = smp + (size_t)b * NN * 3;
    const float* Nr = nrm + (size_t)b * NN * 3;
    const int n0 = pb * 4096;
#pragma unroll 2
    for (int i = 0; i < 16; ++i) {
        int n = n0 + i * 256 + threadIdx.x;
        int c = idx[b * NN + n];
        float sx = S[n * 3 + 0], sy = S[n * 3 + 1], sz = S[n * 3 + 2];
        float nx = Nr[n * 3 + 0], ny = Nr[n * 3 + 1], nz = Nr[n * 3 + 2];
        float d = -(nx * sx + ny * sy + nz * sz);
        float* t = &tab[c * NPC];
        atomicAdd(&t[0], nx * nx); atomicAdd(&t[1], nx * ny); atomicAdd(&t[2], nx * nz);
        atomicAdd(&t[3], ny * ny); atomicAdd(&t[4], ny * nz); atomicAdd(&t[5], nz * nz);
        atomicAdd(&t[6], nx * d);  atomicAdd(&t[7], ny * d);  atomicAdd(&t[8], nz * d);
        atomicAdd(&t[9], nx);      atomicAdd(&t[10], ny);     atomicAdd(&t[11], nz);
        atomicAdd(&t[12], 1.0f);
    }
    __syncthreads();

    float* dst = partial + (size_t)(b * PBLK + pb) * (MM * NPC);
    for (int i = threadIdx.x; i < MM * NPC; i += 256) dst[i] = tab[i];
}

// ---------------------------------------------------------------------------
// Kernel 3: per-cluster finish — one thread per cluster: sum 16 partials,
// fp64 Jacobi eigensolve, outputs.
// ---------------------------------------------------------------------------

#define ROTJ(APP, AQQ, APQ, ARP, ARQ, V0P, V1P, V2P, V0Q, V1Q, V2Q)            \
    do {                                                                       \
        double apq_ = APQ;                                                     \
        if (fabs(apq_) > 1e-300) {                                             \
            double theta_ = (AQQ - APP) / (2.0 * apq_);                        \
            double t_ = 1.0 / (fabs(theta_) + sqrt(theta_ * theta_ + 1.0));    \
            if (theta_ < 0.0) t_ = -t_;                                        \
            double c_ = 1.0 / sqrt(t_ * t_ + 1.0), sn_ = t_ * c_;              \
            APP -= t_ * apq_; AQQ += t_ * apq_; APQ = 0.0;                     \
            double arp_ = ARP, arq_ = ARQ;                                     \
            ARP = c_ * arp_ - sn_ * arq_;                                      \
            ARQ = sn_ * arp_ + c_ * arq_;                                      \
            double x_;                                                         \
            x_ = V0P; V0P = c_ * x_ - sn_ * V0Q; V0Q = sn_ * x_ + c_ * V0Q;    \
            x_ = V1P; V1P = c_ * x_ - sn_ * V1Q; V1Q = sn_ * x_ + c_ * V1Q;    \
            x_ = V2P; V2P = c_ * x_ - sn_ * V2Q; V2Q = sn_ * x_ + c_ * V2Q;    \
        }                                                                      \
    } while (0)

#define CESWAP(EI, EJ, VA, VB, VC, WA, WB, WC)                                 \
    do {                                                                       \
        if (EI < EJ) {                                                         \
            double tt_;                                                        \
            tt_ = EI; EI = EJ; EJ = tt_;                                       \
            tt_ = VA; VA = WA; WA = tt_;                                       \
            tt_ = VB; VB = WB; WB = tt_;                                       \
            tt_ = VC; VC = WC; WC = tt_;                                       \
        }                                                                      \
    } while (0)

__global__ __launch_bounds__(256) void k_finish(
    const float* __restrict__ pp, const float* __restrict__ partial,
    float* __restrict__ out)
{
    const int c = blockIdx.x * 256 + threadIdx.x;   // global cluster [0, CL)
    const int b = c >> 10;
    const int cl = c & (MM - 1);

    float v0 = 0, v1 = 0, v2 = 0, v3 = 0, v4 = 0, v5 = 0, v6 = 0,
          v7 = 0, v8 = 0, v9 = 0, v10 = 0, v11 = 0, v12 = 0;
    for (int p = 0; p < PBLK; ++p) {
        const float* src = partial + ((size_t)(b * PBLK + p) * MM + cl) * NPC;
        v0 += src[0];  v1 += src[1];  v2 += src[2];
        v3 += src[3];  v4 += src[4];  v5 += src[5];
        v6 += src[6];  v7 += src[7];  v8 += src[8];
        v9 += src[9];  v10 += src[10]; v11 += src[11];
        v12 += src[12];
    }

    const int count = (int)v12;
    double denom = count > 1 ? (double)count : 1.0;
    double A00 = v0 / denom, A01 = v1 / denom, A02 = v2 / denom;
    double A11 = v3 / denom, A12 = v4 / denom, A22 = v5 / denom;
    double bv0 = -v6 / denom, bv1 = -v7 / denom, bv2 = -v8 / denom;
    double mn0 = v9 / denom, mn1 = v10 / denom, mn2 = v11 / denom;
    bool nonvoid = (mn0 * mn0 + mn1 * mn1 + mn2 * mn2) > 0.0;

    double vs0 = 0, vs1 = 0, vs2 = 0;
    if (nonvoid) {
        double a00 = A00, a01 = A01, a02 = A02, a11 = A11, a12 = A12, a22 = A22;
        double v00 = 1, v01 = 0, v02 = 0;
        double v10_ = 0, v11_ = 1, v12_ = 0;
        double v20 = 0, v21 = 0, v22 = 1;
#pragma unroll
        for (int sweep = 0; sweep < 8; ++sweep) {
            ROTJ(a00, a11, a01, a02, a12, v00, v10_, v20, v01, v11_, v21);
            ROTJ(a00, a22, a02, a01, a12, v00, v10_, v20, v02, v12_, v22);
            ROTJ(a11, a22, a12, a01, a02, v01, v11_, v21, v02, v12_, v22);
        }
        double e0 = a00, e1 = a11, e2 = a22;
        CESWAP(e0, e1, v00, v10_, v20, v01, v11_, v21);
        CESWAP(e0, e2, v00, v10_, v20, v02, v12_, v22);
        CESWAP(e1, e2, v01, v11_, v21, v02, v12_, v22);

        double emax = e0 > 1e-20 ? e0 : 1e-20;
        const float* Pp = pp + (size_t)c * 3;
        double px = Pp[0], py = Pp[1], pz = Pp[2];
        double r0 = bv0 - (A00 * px + A01 * py + A02 * pz);
        double r1 = bv1 - (A01 * px + A11 * py + A12 * pz);
        double r2 = bv2 - (A02 * px + A12 * py + A22 * pz);
        double thr = 0.01 * emax;
        if (e0 > thr) { double w = (v00 * r0 + v10_ * r1 + v20 * r2) / e0; vs0 += w * v00; vs1 += w * v10_; vs2 += w * v20; }
        if (e1 > thr) { double w = (v01 * r0 + v11_ * r1 + v21 * r2) / e1; vs0 += w * v01; vs1 += w * v11_; vs2 += w * v21; }
        if (e2 > thr) { double w = (v02 * r0 + v12_ * r1 + v22 * r2) / e2; vs0 += w * v02; vs1 += w * v12_; vs2 += w * v22; }
        vs0 += px; vs1 += py; vs2 += pz;
    }

    float* Ao = out + (size_t)c * 9;
    Ao[0] = (float)A00; Ao[1] = (float)A01; Ao[2] = (float)A02;
    Ao[3] = (float)A01; Ao[4] = (float)A11; Ao[5] = (float)A12;
    Ao[6] = (float)A02; Ao[7] = (float)A12; Ao[8] = (float)A22;
    float* Mo = out + 36864 + (size_t)c * 3;
    Mo[0] = (float)mn0; Mo[1] = (float)mn1; Mo[2] = (float)mn2;
    float* Vo = out + 49152 + (size_t)c * 3;
    Vo[0] = (float)vs0; Vo[1] = (float)vs1; Vo[2] = (float)vs2;
    out[61440 + c] = nonvoid ? 1.0f : 0.0f;
}

// ---------------------------------------------------------------------------
extern "C" void kernel_launch(void* const* d_in, const int* in_sizes, int n_in,
                              void* d_out, int out_size, void* d_ws, size_t ws_size,
                              hipStream_t stream)
{
    const float* pp  = (const float*)d_in[0];   // (B,M,3)
    const float* smp = (const float*)d_in[1];   // (B,N,3)
    const float* nrm = (const float*)d_in[2];   // (B,N,3)
    float* out = (float*)d_out;

    char* ws = (char*)d_ws;
    int*   idx     = (int*)ws;                              // B*N ints (1 MB)
    float* partial = (float*)(ws + (size_t)BB * NN * 4);    // 64*1024*13 fp32 (3.4 MB)

    k_assign<<<512, 512, 0, stream>>>(pp, smp, idx);
    k_accum<<<BB * PBLK, 256, 0, stream>>>(idx, smp, nrm, partial);
    k_finish<<<CL / 256, 256, 0, stream>>>(pp, partial, out);
}

// Round 15
// 116.690 us; speedup vs baseline: 1.0057x; 1.0057x over previous
//
#include <hip/hip_runtime.h>

#define BB 4
#define MM 1024
#define NN 65536
#define CL (BB * MM)   // 4096 clusters
#define NPC 13         // 6 quadric + 3 n*d + 3 n + count
#define PBLK 16        // partial blocks per batch

// ---------------------------------------------------------------------------
// Kernel 1: argmin over M. K=8 samples/thread (one broadcast ds_read_b128
// feeds 8 score FMAs), split-M x8 (wave g scans m in [g*128,(g+1)*128)).
// 512 blocks x 512 threads. Writes idx only (no atomics).
// ---------------------------------------------------------------------------
__global__ __launch_bounds__(512) void k_assign(
    const float* __restrict__ pp, const float* __restrict__ smp,
    int* __restrict__ idx)
{
    __shared__ float4 pts[MM];
    __shared__ float bestSh[8][512];
    __shared__ int   biSh[8][512];

    const int b   = blockIdx.x >> 7;    // 128 blocks per batch
    const int blk = blockIdx.x & 127;   // each block: 512 samples
    const float* P = pp + b * MM * 3;
    for (int i = threadIdx.x; i < MM; i += 512) {
        float x = P[i * 3 + 0], y = P[i * 3 + 1], z = P[i * 3 + 2];
        pts[i] = make_float4(x, y, z, x * x + y * y + z * z);
    }
    __syncthreads();

    const int l  = threadIdx.x & 63;
    const int g  = threadIdx.x >> 6;           // wave id = M-octant
    const int nb = blk * 512;
    const float* S = smp + (size_t)b * NN * 3;

    float ax[8], ay[8], az[8], best[8];
    int bi[8];
#pragma unroll
    for (int j = 0; j < 8; ++j) {
        int n = nb + j * 64 + l;
        ax[j] = -2.0f * S[n * 3 + 0];
        ay[j] = -2.0f * S[n * 3 + 1];
        az[j] = -2.0f * S[n * 3 + 2];
        best[j] = 3.4e38f;
        bi[j] = 0;
    }
    const int m0 = g * 128;
#pragma unroll 2
    for (int mi = 0; mi < 128; ++mi) {
        float4 p = pts[m0 + mi];
#pragma unroll
        for (int j = 0; j < 8; ++j) {
            float sc = fmaf(ax[j], p.x, fmaf(ay[j], p.y, fmaf(az[j], p.z, p.w)));
            if (sc < best[j]) { best[j] = sc; bi[j] = m0 + mi; }
        }
    }
#pragma unroll
    for (int j = 0; j < 8; ++j) {
        bestSh[g][j * 64 + l] = best[j];
        biSh[g][j * 64 + l]   = bi[j];
    }
    __syncthreads();

    {
        const int t = threadIdx.x;             // sample-local id in [0,512)
        float bb = bestSh[0][t];
        int   ii = biSh[0][t];
#pragma unroll
        for (int gg = 1; gg < 8; ++gg) {
            float bo = bestSh[gg][t];
            int   io = biSh[gg][t];
            if (bo < bb) { bb = bo; ii = io; } // tie -> lower g = lower m
        }
        idx[b * NN + nb + t] = ii;
    }
}

// ---------------------------------------------------------------------------
// Kernel 2: per-block LDS accumulation of the 13 per-cluster sums.
// 64 blocks x 512 threads (8 waves); each block covers 4096 samples of one
// batch. unsafeAtomicAdd -> native ds_add_f32 (no CAS loop). Stride-13 table
// is coprime with 32 banks -> low conflicts. Partials fully overwritten.
// ---------------------------------------------------------------------------
__global__ __launch_bounds__(512) void k_accum(
    const int* __restrict__ idx, const float* __restrict__ smp,
    const float* __restrict__ nrm, float* __restrict__ partial)
{
    __shared__ float tab[MM * NPC];     // 53248 B
    const int b  = blockIdx.x >> 4;     // batch
    const int pb = blockIdx.x & 15;     // partial-block within batch
    for (int i = threadIdx.x; i < MM * NPC; i += 512) tab[i] = 0.0f;
    __syncthreads();

    const float* S  = smp + (size_t)b * NN * 3;
    const float* Nr = nrm + (size_t)b * NN * 3;
    const int n0 = pb * 4096;
#pragma unroll 2
    for (int i = 0; i < 8; ++i) {
        int n = n0 + i * 512 + threadIdx.x;
        int c = idx[b * NN + n];
        float sx = S[n * 3 + 0], sy = S[n * 3 + 1], sz = S[n * 3 + 2];
        float nx = Nr[n * 3 + 0], ny = Nr[n * 3 + 1], nz = Nr[n * 3 + 2];
        float d = -(nx * sx + ny * sy + nz * sz);
        float* t = &tab[c * NPC];
        unsafeAtomicAdd(&t[0], nx * nx); unsafeAtomicAdd(&t[1], nx * ny); unsafeAtomicAdd(&t[2], nx * nz);
        unsafeAtomicAdd(&t[3], ny * ny); unsafeAtomicAdd(&t[4], ny * nz); unsafeAtomicAdd(&t[5], nz * nz);
        unsafeAtomicAdd(&t[6], nx * d);  unsafeAtomicAdd(&t[7], ny * d);  unsafeAtomicAdd(&t[8], nz * d);
        unsafeAtomicAdd(&t[9], nx);      unsafeAtomicAdd(&t[10], ny);     unsafeAtomicAdd(&t[11], nz);
        unsafeAtomicAdd(&t[12], 1.0f);
    }
    __syncthreads();

    float* dst = partial + (size_t)(b * PBLK + pb) * (MM * NPC);
    for (int i = threadIdx.x; i < MM * NPC; i += 512) dst[i] = tab[i];
}

// ---------------------------------------------------------------------------
// Kernel 3: per-cluster finish — one thread per cluster: sum 16 partials
// (3x float4 + 1 scalar loads per partial), fp64 Jacobi eigensolve, outputs.
// ---------------------------------------------------------------------------

#define ROTJ(APP, AQQ, APQ, ARP, ARQ, V0P, V1P, V2P, V0Q, V1Q, V2Q)            \
    do {                                                                       \
        double apq_ = APQ;                                                     \
        if (fabs(apq_) > 1e-300) {                                             \
            double theta_ = (AQQ - APP) / (2.0 * apq_);                        \
            double t_ = 1.0 / (fabs(theta_) + sqrt(theta_ * theta_ + 1.0));    \
            if (theta_ < 0.0) t_ = -t_;                                        \
            double c_ = 1.0 / sqrt(t_ * t_ + 1.0), sn_ = t_ * c_;              \
            APP -= t_ * apq_; AQQ += t_ * apq_; APQ = 0.0;                     \
            double arp_ = ARP, arq_ = ARQ;                                     \
            ARP = c_ * arp_ - sn_ * arq_;                                      \
            ARQ = sn_ * arp_ + c_ * arq_;                                      \
            double x_;                                                         \
            x_ = V0P; V0P = c_ * x_ - sn_ * V0Q; V0Q = sn_ * x_ + c_ * V0Q;    \
            x_ = V1P; V1P = c_ * x_ - sn_ * V1Q; V1Q = sn_ * x_ + c_ * V1Q;    \
            x_ = V2P; V2P = c_ * x_ - sn_ * V2Q; V2Q = sn_ * x_ + c_ * V2Q;    \
        }                                                                      \
    } while (0)

#define CESWAP(EI, EJ, VA, VB, VC, WA, WB, WC)                                 \
    do {                                                                       \
        if (EI < EJ) {                                                         \
            double tt_;                                                        \
            tt_ = EI; EI = EJ; EJ = tt_;                                       \
            tt_ = VA; VA = WA; WA = tt_;                                       \
            tt_ = VB; VB = WB; WB = tt_;                                       \
            tt_ = VC; VC = WC; WC = tt_;                                       \
        }                                                                      \
    } while (0)

__global__ __launch_bounds__(256) void k_finish(
    const float* __restrict__ pp, const float* __restrict__ partial,
    float* __restrict__ out)
{
    const int c = blockIdx.x * 256 + threadIdx.x;   // global cluster [0, CL)
    const int b = c >> 10;
    const int cl = c & (MM - 1);

    float v0 = 0, v1 = 0, v2 = 0, v3 = 0, v4 = 0, v5 = 0, v6 = 0,
          v7 = 0, v8 = 0, v9 = 0, v10 = 0, v11 = 0, v12 = 0;
    for (int p = 0; p < PBLK; ++p) {
        const float* src = partial + ((size_t)(b * PBLK + p) * MM + cl) * NPC;
        float4 a = *(const float4*)(src + 0);
        float4 bq = *(const float4*)(src + 4);
        float4 cq = *(const float4*)(src + 8);
        v0 += a.x;  v1 += a.y;  v2 += a.z;  v3 += a.w;
        v4 += bq.x; v5 += bq.y; v6 += bq.z; v7 += bq.w;
        v8 += cq.x; v9 += cq.y; v10 += cq.z; v11 += cq.w;
        v12 += src[12];
    }

    const int count = (int)v12;
    double denom = count > 1 ? (double)count : 1.0;
    double A00 = v0 / denom, A01 = v1 / denom, A02 = v2 / denom;
    double A11 = v3 / denom, A12 = v4 / denom, A22 = v5 / denom;
    double bv0 = -v6 / denom, bv1 = -v7 / denom, bv2 = -v8 / denom;
    double mn0 = v9 / denom, mn1 = v10 / denom, mn2 = v11 / denom;
    bool nonvoid = (mn0 * mn0 + mn1 * mn1 + mn2 * mn2) > 0.0;

    double vs0 = 0, vs1 = 0, vs2 = 0;
    if (nonvoid) {
        double a00 = A00, a01 = A01, a02 = A02, a11 = A11, a12 = A12, a22 = A22;
        double v00 = 1, v01 = 0, v02 = 0;
        double v10_ = 0, v11_ = 1, v12_ = 0;
        double v20 = 0, v21 = 0, v22 = 1;
#pragma unroll
        for (int sweep = 0; sweep < 8; ++sweep) {
            ROTJ(a00, a11, a01, a02, a12, v00, v10_, v20, v01, v11_, v21);
            ROTJ(a00, a22, a02, a01, a12, v00, v10_, v20, v02, v12_, v22);
            ROTJ(a11, a22, a12, a01, a02, v01, v11_, v21, v02, v12_, v22);
        }
        double e0 = a00, e1 = a11, e2 = a22;
        CESWAP(e0, e1, v00, v10_, v20, v01, v11_, v21);
        CESWAP(e0, e2, v00, v10_, v20, v02, v12_, v22);
        CESWAP(e1, e2, v01, v11_, v21, v02, v12_, v22);

        double emax = e0 > 1e-20 ? e0 : 1e-20;
        const float* Pp = pp + (size_t)c * 3;
        double px = Pp[0], py = Pp[1], pz = Pp[2];
        double r0 = bv0 - (A00 * px + A01 * py + A02 * pz);
        double r1 = bv1 - (A01 * px + A11 * py + A12 * pz);
        double r2 = bv2 - (A02 * px + A12 * py + A22 * pz);
        double thr = 0.01 * emax;
        if (e0 > thr) { double w = (v00 * r0 + v10_ * r1 + v20 * r2) / e0; vs0 += w * v00; vs1 += w * v10_; vs2 += w * v20; }
        if (e1 > thr) { double w = (v01 * r0 + v11_ * r1 + v21 * r2) / e1; vs0 += w * v01; vs1 += w * v11_; vs2 += w * v21; }
        if (e2 > thr) { double w = (v02 * r0 + v12_ * r1 + v22 * r2) / e2; vs0 += w * v02; vs1 += w * v12_; vs2 += w * v22; }
        vs0 += px; vs1 += py; vs2 += pz;
    }

    float* Ao = out + (size_t)c * 9;
    Ao[0] = (float)A00; Ao[1] = (float)A01; Ao[2] = (float)A02;
    Ao[3] = (float)A01; Ao[4] = (float)A11; Ao[5] = (float)A12;
    Ao[6] = (float)A02; Ao[7] = (float)A12; Ao[8] = (float)A22;
    float* Mo = out + 36864 + (size_t)c * 3;
    Mo[0] = (float)mn0; Mo[1] = (float)mn1; Mo[2] = (float)mn2;
    float* Vo = out + 49152 + (size_t)c * 3;
    Vo[0] = (float)vs0; Vo[1] = (float)vs1; Vo[2] = (float)vs2;
    out[61440 + c] = nonvoid ? 1.0f : 0.0f;
}

// ---------------------------------------------------------------------------
extern "C" void kernel_launch(void* const* d_in, const int* in_sizes, int n_in,
                              void* d_out, int out_size, void* d_ws, size_t ws_size,
                              hipStream_t stream)
{
    const float* pp  = (const float*)d_in[0];   // (B,M,3)
    const float* smp = (const float*)d_in[1];   // (B,N,3)
    const float* nrm = (const float*)d_in[2];   // (B,N,3)
    float* out = (float*)d_out;

    char* ws = (char*)d_ws;
    int*   idx     = (int*)ws;                              // B*N ints (1 MB)
    float* partial = (float*)(ws + (size_t)BB * NN * 4);    // 64*1024*13 fp32 (3.4 MB)

    k_assign<<<512, 512, 0, stream>>>(pp, smp, idx);
    k_accum<<<BB * PBLK, 512, 0, stream>>>(idx, smp, nrm, partial);
    k_finish<<<CL / 256, 256, 0, stream>>>(pp, partial, out);
}

// Round 16
// 111.320 us; speedup vs baseline: 1.0542x; 1.0482x over previous
//
#include <hip/hip_runtime.h>

#define BB 4
#define MM 1024
#define NN 65536
#define CL (BB * MM)   // 4096 clusters
#define NPC 13         // 6 quadric + 3 n*d + 3 n + count

// ---------------------------------------------------------------------------
// Kernel 1: argmin over M. K=8 samples/thread (one broadcast ds_read_b128
// feeds 8 score FMAs), split-M x8 (wave g scans m in [g*128,(g+1)*128)).
// 512 blocks x 512 threads. Writes idx only (no atomics).
// ---------------------------------------------------------------------------
__global__ __launch_bounds__(512) void k_assign(
    const float* __restrict__ pp, const float* __restrict__ smp,
    int* __restrict__ idx)
{
    __shared__ float4 pts[MM];
    __shared__ float bestSh[8][512];
    __shared__ int   biSh[8][512];

    const int b   = blockIdx.x >> 7;    // 128 blocks per batch
    const int blk = blockIdx.x & 127;   // each block: 512 samples
    const float* P = pp + b * MM * 3;
    for (int i = threadIdx.x; i < MM; i += 512) {
        float x = P[i * 3 + 0], y = P[i * 3 + 1], z = P[i * 3 + 2];
        pts[i] = make_float4(x, y, z, x * x + y * y + z * z);
    }
    __syncthreads();

    const int l  = threadIdx.x & 63;
    const int g  = threadIdx.x >> 6;           // wave id = M-octant
    const int nb = blk * 512;
    const float* S = smp + (size_t)b * NN * 3;

    float ax[8], ay[8], az[8], best[8];
    int bi[8];
#pragma unroll
    for (int j = 0; j < 8; ++j) {
        int n = nb + j * 64 + l;
        ax[j] = -2.0f * S[n * 3 + 0];
        ay[j] = -2.0f * S[n * 3 + 1];
        az[j] = -2.0f * S[n * 3 + 2];
        best[j] = 3.4e38f;
        bi[j] = 0;
    }
    const int m0 = g * 128;
#pragma unroll 2
    for (int mi = 0; mi < 128; ++mi) {
        float4 p = pts[m0 + mi];
#pragma unroll
        for (int j = 0; j < 8; ++j) {
            float sc = fmaf(ax[j], p.x, fmaf(ay[j], p.y, fmaf(az[j], p.z, p.w)));
            if (sc < best[j]) { best[j] = sc; bi[j] = m0 + mi; }
        }
    }
#pragma unroll
    for (int j = 0; j < 8; ++j) {
        bestSh[g][j * 64 + l] = best[j];
        biSh[g][j * 64 + l]   = bi[j];
    }
    __syncthreads();

    {
        const int t = threadIdx.x;             // sample-local id in [0,512)
        float bb = bestSh[0][t];
        int   ii = biSh[0][t];
#pragma unroll
        for (int gg = 1; gg < 8; ++gg) {
            float bo = bestSh[gg][t];
            int   io = biSh[gg][t];
            if (bo < bb) { bb = bo; ii = io; } // tie -> lower g = lower m
        }
        idx[b * NN + nb + t] = ii;
    }
}

// ---------------------------------------------------------------------------
// Kernel 2 (fused reduce+finish): cluster-major. Each of 256 blocks owns 16
// clusters of one batch; scans the batch's idx[] (coalesced, execz-skip when
// no lane hits), native ds_add_f32 into a 16x13 LDS table (~1 active
// lane/wave-op -> no contention), then threads 0..15 run fp64 Jacobi and
// write all outputs for their cluster.
// ---------------------------------------------------------------------------

#define ROTJ(APP, AQQ, APQ, ARP, ARQ, V0P, V1P, V2P, V0Q, V1Q, V2Q)            \
    do {                                                                       \
        double apq_ = APQ;                                                     \
        if (fabs(apq_) > 1e-300) {                                             \
            double theta_ = (AQQ - APP) / (2.0 * apq_);                        \
            double t_ = 1.0 / (fabs(theta_) + sqrt(theta_ * theta_ + 1.0));    \
            if (theta_ < 0.0) t_ = -t_;                                        \
            double c_ = 1.0 / sqrt(t_ * t_ + 1.0), sn_ = t_ * c_;              \
            APP -= t_ * apq_; AQQ += t_ * apq_; APQ = 0.0;                     \
            double arp_ = ARP, arq_ = ARQ;                                     \
            ARP = c_ * arp_ - sn_ * arq_;                                      \
            ARQ = sn_ * arp_ + c_ * arq_;                                      \
            double x_;                                                         \
            x_ = V0P; V0P = c_ * x_ - sn_ * V0Q; V0Q = sn_ * x_ + c_ * V0Q;    \
            x_ = V1P; V1P = c_ * x_ - sn_ * V1Q; V1Q = sn_ * x_ + c_ * V1Q;    \
            x_ = V2P; V2P = c_ * x_ - sn_ * V2Q; V2Q = sn_ * x_ + c_ * V2Q;    \
        }                                                                      \
    } while (0)

#define CESWAP(EI, EJ, VA, VB, VC, WA, WB, WC)                                 \
    do {                                                                       \
        if (EI < EJ) {                                                         \
            double tt_;                                                        \
            tt_ = EI; EI = EJ; EJ = tt_;                                       \
            tt_ = VA; VA = WA; WA = tt_;                                       \
            tt_ = VB; VB = WB; WB = tt_;                                       \
            tt_ = VC; VC = WC; WC = tt_;                                       \
        }                                                                      \
    } while (0)

__global__ __launch_bounds__(512) void k_reduce(
    const float* __restrict__ pp, const float* __restrict__ smp,
    const float* __restrict__ nrm, const int* __restrict__ idx,
    float* __restrict__ out)
{
    __shared__ float tab[16 * NPC];     // 208 floats
    const int b  = blockIdx.x >> 6;     // 64 blocks per batch
    const int cb = blockIdx.x & 63;     // cluster-block within batch
    const int c0 = cb * 16;
    for (int i = threadIdx.x; i < 16 * NPC; i += 512) tab[i] = 0.0f;
    __syncthreads();

    const float* S  = smp + (size_t)b * NN * 3;
    const float* Nr = nrm + (size_t)b * NN * 3;
    const int*   I  = idx + (size_t)b * NN;
    const unsigned tb = (unsigned)(uintptr_t)&tab[0];

    for (int i = 0; i < 128; ++i) {
        const int n = i * 512 + threadIdx.x;
        const unsigned c = (unsigned)(I[n] - c0);
        if (c < 16u) {
            float sx = S[n * 3 + 0], sy = S[n * 3 + 1], sz = S[n * 3 + 2];
            float nx = Nr[n * 3 + 0], ny = Nr[n * 3 + 1], nz = Nr[n * 3 + 2];
            float d = -(nx * sx + ny * sy + nz * sz);
            unsigned a = tb + c * (NPC * 4);
#define DSADD(OFF, VAL) \
            asm volatile("ds_add_f32 %0, %1 offset:" #OFF :: "v"(a), "v"(VAL) : "memory")
            DSADD(0,  nx * nx); DSADD(4,  nx * ny); DSADD(8,  nx * nz);
            DSADD(12, ny * ny); DSADD(16, ny * nz); DSADD(20, nz * nz);
            DSADD(24, nx * d);  DSADD(28, ny * d);  DSADD(32, nz * d);
            DSADD(36, nx);      DSADD(40, ny);      DSADD(44, nz);
            DSADD(48, 1.0f);
#undef DSADD
        }
    }
    __syncthreads();

    if (threadIdx.x < 16) {
        const int j = threadIdx.x;
        const float* t = &tab[j * NPC];
        const int gc = b * MM + c0 + j;            // global cluster id

        const int count = (int)t[12];
        double denom = count > 1 ? (double)count : 1.0;
        double A00 = t[0] / denom, A01 = t[1] / denom, A02 = t[2] / denom;
        double A11 = t[3] / denom, A12 = t[4] / denom, A22 = t[5] / denom;
        double bv0 = -t[6] / denom, bv1 = -t[7] / denom, bv2 = -t[8] / denom;
        double mn0 = t[9] / denom, mn1 = t[10] / denom, mn2 = t[11] / denom;
        bool nonvoid = (mn0 * mn0 + mn1 * mn1 + mn2 * mn2) > 0.0;

        double vs0 = 0, vs1 = 0, vs2 = 0;
        if (nonvoid) {
            double a00 = A00, a01 = A01, a02 = A02, a11 = A11, a12 = A12, a22 = A22;
            double v00 = 1, v01 = 0, v02 = 0;
            double v10 = 0, v11 = 1, v12 = 0;
            double v20 = 0, v21 = 0, v22 = 1;
#pragma unroll
            for (int sweep = 0; sweep < 8; ++sweep) {
                ROTJ(a00, a11, a01, a02, a12, v00, v10, v20, v01, v11, v21);
                ROTJ(a00, a22, a02, a01, a12, v00, v10, v20, v02, v12, v22);
                ROTJ(a11, a22, a12, a01, a02, v01, v11, v21, v02, v12, v22);
            }
            double e0 = a00, e1 = a11, e2 = a22;
            CESWAP(e0, e1, v00, v10, v20, v01, v11, v21);
            CESWAP(e0, e2, v00, v10, v20, v02, v12, v22);
            CESWAP(e1, e2, v01, v11, v21, v02, v12, v22);

            double emax = e0 > 1e-20 ? e0 : 1e-20;
            const float* Pp = pp + (size_t)gc * 3;
            double px = Pp[0], py = Pp[1], pz = Pp[2];
            double r0 = bv0 - (A00 * px + A01 * py + A02 * pz);
            double r1 = bv1 - (A01 * px + A11 * py + A12 * pz);
            double r2 = bv2 - (A02 * px + A12 * py + A22 * pz);
            double thr = 0.01 * emax;
            if (e0 > thr) { double w = (v00 * r0 + v10 * r1 + v20 * r2) / e0; vs0 += w * v00; vs1 += w * v10; vs2 += w * v20; }
            if (e1 > thr) { double w = (v01 * r0 + v11 * r1 + v21 * r2) / e1; vs0 += w * v01; vs1 += w * v11; vs2 += w * v21; }
            if (e2 > thr) { double w = (v02 * r0 + v12 * r1 + v22 * r2) / e2; vs0 += w * v02; vs1 += w * v12; vs2 += w * v22; }
            vs0 += px; vs1 += py; vs2 += pz;
        }

        float* Ao = out + (size_t)gc * 9;
        Ao[0] = (float)A00; Ao[1] = (float)A01; Ao[2] = (float)A02;
        Ao[3] = (float)A01; Ao[4] = (float)A11; Ao[5] = (float)A12;
        Ao[6] = (float)A02; Ao[7] = (float)A12; Ao[8] = (float)A22;
        float* Mo = out + 36864 + (size_t)gc * 3;
        Mo[0] = (float)mn0; Mo[1] = (float)mn1; Mo[2] = (float)mn2;
        float* Vo = out + 49152 + (size_t)gc * 3;
        Vo[0] = (float)vs0; Vo[1] = (float)vs1; Vo[2] = (float)vs2;
        out[61440 + gc] = nonvoid ? 1.0f : 0.0f;
    }
}

// ---------------------------------------------------------------------------
extern "C" void kernel_launch(void* const* d_in, const int* in_sizes, int n_in,
                              void* d_out, int out_size, void* d_ws, size_t ws_size,
                              hipStream_t stream)
{
    const float* pp  = (const float*)d_in[0];   // (B,M,3)
    const float* smp = (const float*)d_in[1];   // (B,N,3)
    const float* nrm = (const float*)d_in[2];   // (B,N,3)
    float* out = (float*)d_out;

    int* idx = (int*)d_ws;                      // B*N ints (1 MB)

    k_assign<<<512, 512, 0, stream>>>(pp, smp, idx);
    k_reduce<<<BB * 64, 512, 0, stream>>>(pp, smp, nrm, idx, out);
}